// Round 3
// baseline (588.038 us; speedup 1.0000x reference)
//
#include <hip/hip_runtime.h>
#include <math.h>

#define NB 8
#define NC 256
#define ND 32
#define NN 4096
#define NM 320                 // fused rows: 32 q + 32 k + 256 v
#define LOG2E 1.44269504088896f
#define XSTR 264               // proj LDS row stride (shorts), 16B-aligned rows

typedef short short8 __attribute__((ext_vector_type(8)));
typedef short short4v __attribute__((ext_vector_type(4)));
typedef float f32x4 __attribute__((ext_vector_type(4)));

__device__ __forceinline__ unsigned int f2bf_u(float f) {
    return (__float_as_uint(f) + 0x8000u) >> 16;
}
__device__ __forceinline__ unsigned short f2bf(float f) {
    return (unsigned short)f2bf_u(f);
}

// ---------------------------------------------------------------------------
// Repack fused weights [320x256] -> bf16 fragments.  Rows 0..31 = Wq*LOG2E,
// 32..63 = Wk, 64..319 = Wv.  Also bias[320].
// ---------------------------------------------------------------------------
__global__ __launch_bounds__(256) void repack_kernel(
    const float* __restrict__ Wq, const float* __restrict__ bq,
    const float* __restrict__ Wk, const float* __restrict__ bk,
    const float* __restrict__ Wv, const float* __restrict__ bv,
    unsigned short* __restrict__ wp, float* __restrict__ bias)
{
    const int T    = blockIdx.x * 256 + threadIdx.x;   // 81920 threads
    const int j    = T & 7;
    const int lane = (T >> 3) & 63;
    const int ks   = (T >> 9) & 7;
    const int mt   = T >> 12;
    const int m = mt * 16 + (lane & 15);
    const int k = ks * 32 + ((lane >> 4) << 3) + j;
    float wv;
    if (m < 32)       wv = Wq[m * NC + k] * LOG2E;
    else if (m < 64)  wv = Wk[(m - 32) * NC + k];
    else              wv = Wv[(m - 64) * NC + k];
    wp[T] = f2bf(wv);
    if (T < NM) {
        float bb;
        if (T < 32)      bb = bq[T] * LOG2E;
        else if (T < 64) bb = bk[T - 32];
        else             bb = bv[T - 64];
        bias[T] = bb;
    }
}

// ---------------------------------------------------------------------------
// MFMA projection (unchanged): A = x (m = pixel), B = W^T.
// ---------------------------------------------------------------------------
__global__ __launch_bounds__(256, 4) void proj_kernel(
    const float* __restrict__ x,
    const unsigned short* __restrict__ wp,
    const float* __restrict__ bias,
    unsigned short* __restrict__ q_ws,
    unsigned short* __restrict__ k_ws,
    unsigned short* __restrict__ v_ws)
{
    __shared__ __align__(16) unsigned short xs[32 * XSTR];   // 16.9 KB

    const int b  = blockIdx.x >> 7;          // 128 tiles per batch
    const int n0 = (blockIdx.x & 127) << 5;
    const int t  = threadIdx.x;

    {
        const int n  = t & 31;
        const int cg = t >> 5;               // 0..7
        const float* xb = x + (size_t)b * NC * NN + n0 + n;
        #pragma unroll
        for (int it = 0; it < 8; ++it) {
            const int c = 32 * it + 4 * cg;
            const float x0 = xb[(size_t)(c + 0) * NN];
            const float x1 = xb[(size_t)(c + 1) * NN];
            const float x2 = xb[(size_t)(c + 2) * NN];
            const float x3 = xb[(size_t)(c + 3) * NN];
            uint2 pk;
            pk.x = (f2bf_u(x1) << 16) | f2bf_u(x0);
            pk.y = (f2bf_u(x3) << 16) | f2bf_u(x2);
            *(uint2*)(xs + n * XSTR + c) = pk;
        }
    }
    __syncthreads();

    const int w    = t >> 6;
    const int lane = t & 63;
    const int li = lane & 15;
    const int qd = lane >> 4;

    f32x4 acc[5][2];
    #pragma unroll
    for (int u = 0; u < 5; ++u) {
        const float bb = bias[(w + 4 * u) * 16 + li];
        acc[u][0] = (f32x4){bb, bb, bb, bb};
        acc[u][1] = (f32x4){bb, bb, bb, bb};
    }

    #pragma unroll
    for (int ks = 0; ks < 8; ++ks) {
        short8 af[2];
        #pragma unroll
        for (int mt = 0; mt < 2; ++mt)
            af[mt] = *(const short8*)(xs + (mt * 16 + li) * XSTR + ks * 32 + qd * 8);
        #pragma unroll
        for (int u = 0; u < 5; ++u) {
            const int ct = w + 4 * u;
            const short8 bf = *(const short8*)(wp + (size_t)((ct * 8 + ks) * 64 + lane) * 8);
            acc[u][0] = __builtin_amdgcn_mfma_f32_16x16x32_bf16(af[0], bf, acc[u][0], 0, 0, 0);
            acc[u][1] = __builtin_amdgcn_mfma_f32_16x16x32_bf16(af[1], bf, acc[u][1], 0, 0, 0);
        }
    }

    #pragma unroll
    for (int u = 0; u < 5; ++u) {
        const int ct = w + 4 * u;
        if (ct < 4) {
            unsigned short* dst = (ct < 2) ? q_ws : k_ws;
            const int d = (ct & 1) * 16 + li;
            #pragma unroll
            for (int mt = 0; mt < 2; ++mt)
                #pragma unroll
                for (int r = 0; r < 4; ++r) {
                    const int n = n0 + mt * 16 + 4 * qd + r;
                    dst[((size_t)b * NN + n) * ND + d] = f2bf(acc[u][mt][r]);
                }
        } else {
            const int cv = (ct - 4) * 16 + li;
            #pragma unroll
            for (int mt = 0; mt < 2; ++mt) {
                const int n = n0 + mt * 16 + 4 * qd;
                uint2 pk;
                pk.x = (f2bf_u(acc[u][mt][1]) << 16) | f2bf_u(acc[u][mt][0]);
                pk.y = (f2bf_u(acc[u][mt][3]) << 16) | f2bf_u(acc[u][mt][2]);
                *(uint2*)(v_ws + ((size_t)b * NC + cv) * NN + n) = pk;
            }
        }
    }
}

// ---------------------------------------------------------------------------
// Flash attention R10: BARRIER-FREE, LDS-FREE.  4 independent waves per
// 256-thr block; wave w owns the FULL 64-row i-tile x 64 channels (c0=64w).
//
// R7/R8/R9 lesson: per-chunk time (~6150 cyc) was invariant to LDS traffic,
// occupancy, ILP and barrier count while every pipe sat at ~20% -> the
// producer->LDS->barrier->consumer P broadcast itself was the floor.
//
// Key layout identity: S = mfma_16x16x32(K, Q) leaves lane (li,qd) holding
// S[i=li][j=16jt+4qd+r].  exp2+pack gives pk = {bf16(p0,p1), bf16(p2,p3)}
// = EXACTLY the B-operand fragment of v_mfma_f32_16x16x16_bf16
// (B[k=qd*4+e][col=li]).  So PV at K=16 consumes P fully lane-locally:
// S-MFMA -> exp2 -> pack -> PV-MFMA, zero cross-lane traffic, zero LDS,
// zero barriers.  Cost: S recomputed per channel-group (4x) — S is only
// 11% of the FLOPs.  V traffic per block unchanged (waves split channels).
// ---------------------------------------------------------------------------
__global__ __launch_bounds__(256, 2) void attn_kernel(
    const unsigned short* __restrict__ q_ws,
    const unsigned short* __restrict__ k_ws,
    const unsigned short* __restrict__ v_ws,
    float* __restrict__ out)
{
    const int b  = blockIdx.x & 7;           // batch == XCD
    const int i0 = (blockIdx.x >> 3) * 64;
    const int w    = threadIdx.x >> 6;       // 0..3
    const int lane = threadIdx.x & 63;
    const int li = lane & 15;
    const int qd = lane >> 4;
    const int c0 = 64 * w;                   // channel slice (64 ch)

    // Q fragments for the 4 i-strips (B-operand of S-MFMA: col=i, k=d)
    short8 qf[4];
    #pragma unroll
    for (int sb = 0; sb < 4; ++sb)
        qf[sb] = *(const short8*)(q_ws + ((size_t)b * NN + i0 + 16 * sb + li) * ND + qd * 8);

    // K base: A-operand of S-MFMA (row=j, k=d)
    const unsigned short* kb = k_ws + ((size_t)b * NN + li) * ND + qd * 8;
    // V bases per c-tile: A-operand of PV-MFMA16 (row=c, k=j -> qd*4)
    const unsigned short* vrow[4];
    #pragma unroll
    for (int ct = 0; ct < 4; ++ct)
        vrow[ct] = v_ws + ((size_t)b * NC + c0 + 16 * ct + li) * NN + qd * 4;

    f32x4 o[4][4];                           // [i-strip][c-tile]
    #pragma unroll
    for (int sb = 0; sb < 4; ++sb)
        #pragma unroll
        for (int ct = 0; ct < 4; ++ct)
            o[sb][ct] = (f32x4){0.f, 0.f, 0.f, 0.f};
    float l_loc[4] = {0.f, 0.f, 0.f, 0.f};
    const f32x4 z4 = {0.f, 0.f, 0.f, 0.f};

    short8 kA[4], kB[4];
    uint2  vA[4][4], vB[4][4];               // [ct][jt], 8B A-frags

    auto LK = [&](int j0, short8 (&kf)[4]) {
        #pragma unroll
        for (int jt = 0; jt < 4; ++jt)
            kf[jt] = *(const short8*)(kb + (size_t)(j0 + 16 * jt) * ND);
    };
    auto LV = [&](int j0, uint2 (&vf)[4][4]) {
        #pragma unroll
        for (int ct = 0; ct < 4; ++ct)
            #pragma unroll
            for (int jt = 0; jt < 4; ++jt)
                vf[ct][jt] = *(const uint2*)(vrow[ct] + j0 + 16 * jt);
    };
    // One 64-j chunk: per strip sb, S (4x 16x16x32) -> exp2 -> pack ->
    // PV (16x 16x16x16, P lane-local).
    auto CHUNK = [&](short8 (&kf)[4], uint2 (&vf)[4][4]) {
        #pragma unroll
        for (int sb = 0; sb < 4; ++sb) {
            uint2 pk[4];
            #pragma unroll
            for (int jt = 0; jt < 4; ++jt) {
                const f32x4 s = __builtin_amdgcn_mfma_f32_16x16x32_bf16(kf[jt], qf[sb], z4, 0, 0, 0);
                const float p0 = __builtin_amdgcn_exp2f(s[0]);
                const float p1 = __builtin_amdgcn_exp2f(s[1]);
                const float p2 = __builtin_amdgcn_exp2f(s[2]);
                const float p3 = __builtin_amdgcn_exp2f(s[3]);
                l_loc[sb] += (p0 + p1) + (p2 + p3);
                const unsigned u0 = __float_as_uint(p0) + 0x8000u;
                const unsigned u1 = __float_as_uint(p1) + 0x8000u;
                const unsigned u2 = __float_as_uint(p2) + 0x8000u;
                const unsigned u3 = __float_as_uint(p3) + 0x8000u;
                pk[jt].x = __builtin_amdgcn_perm(u1, u0, 0x07060302u);
                pk[jt].y = __builtin_amdgcn_perm(u3, u2, 0x07060302u);
            }
            #pragma unroll
            for (int ct = 0; ct < 4; ++ct)
                #pragma unroll
                for (int jt = 0; jt < 4; ++jt)
                    o[sb][ct] = __builtin_amdgcn_mfma_f32_16x16x16bf16_1k(
                        __builtin_bit_cast(short4v, vf[ct][jt]),
                        __builtin_bit_cast(short4v, pk[jt]),
                        o[sb][ct], 0, 0, 0);
        }
    };

    // ---- software pipeline, 1-chunk register prefetch, no barriers ----
    LK(0, kA); LV(0, vA);
    #pragma unroll 1
    for (int it = 0; it < 31; ++it) {
        const int j = it * 128;
        LK(j + 64, kB); LV(j + 64, vB);
        __builtin_amdgcn_sched_barrier(0);   // pin prefetch issue before compute
        CHUNK(kA, vA);
        LK(j + 128, kA); LV(j + 128, vA);
        __builtin_amdgcn_sched_barrier(0);
        CHUNK(kB, vB);
    }
    LK(4032, kB); LV(4032, vB);
    __builtin_amdgcn_sched_barrier(0);
    CHUNK(kA, vA);                           // chunk 62
    CHUNK(kB, vB);                           // chunk 63

    // ---- l reduction: fully intra-wave (sum over qd groups) ----
    #pragma unroll
    for (int sb = 0; sb < 4; ++sb) {
        l_loc[sb] += __shfl_xor(l_loc[sb], 16, 64);
        l_loc[sb] += __shfl_xor(l_loc[sb], 32, 64);
    }

    #pragma unroll
    for (int sb = 0; sb < 4; ++sb) {
        const float linv = 1.0f / l_loc[sb];
        #pragma unroll
        for (int ct = 0; ct < 4; ++ct) {
            const int c = c0 + ct * 16 + qd * 4;
            float* op = out + ((size_t)b * NC + c) * NN + i0 + 16 * sb + li;
            #pragma unroll
            for (int r = 0; r < 4; ++r)
                op[(size_t)r * NN] = o[sb][ct][r] * linv;
        }
    }
}

// ---------------------------------------------------------------------------
extern "C" void kernel_launch(void* const* d_in, const int* in_sizes, int n_in,
                              void* d_out, int out_size, void* d_ws, size_t ws_size,
                              hipStream_t stream) {
    const float* x  = (const float*)d_in[0];
    const float* Wq = (const float*)d_in[1];
    const float* bq = (const float*)d_in[2];
    const float* Wk = (const float*)d_in[3];
    const float* bk = (const float*)d_in[4];
    const float* Wv = (const float*)d_in[5];
    const float* bv = (const float*)d_in[6];
    float* out = (float*)d_out;

    unsigned short* q_ws = (unsigned short*)d_ws;            // 2 MB
    unsigned short* k_ws = q_ws + (size_t)NB * NN * ND;      // 2 MB
    unsigned short* v_ws = k_ws + (size_t)NB * NN * ND;      // 16 MB
    unsigned short* wp   = v_ws + (size_t)NB * NC * NN;      // 160 KB
    float*          bias = (float*)(wp + (size_t)NM * NC);   // 1.25 KB

    repack_kernel<<<NM * NC / 256, 256, 0, stream>>>(Wq, bq, Wk, bk, Wv, bv, wp, bias);
    proj_kernel<<<NB * (NN / 32), 256, 0, stream>>>(x, wp, bias, q_ws, k_ws, v_ws);
    attn_kernel<<<NB * (NN / 64), 256, 0, stream>>>(q_ws, k_ws, v_ws, out);
}

// Round 4
// 359.068 us; speedup vs baseline: 1.6377x; 1.6377x over previous
//
#include <hip/hip_runtime.h>
#include <math.h>

#define NB 8
#define NC 256
#define ND 32
#define NN 4096
#define NM 320                 // fused rows: 32 q + 32 k + 256 v
#define LOG2E 1.44269504088896f
#define XSTR 264               // proj LDS row stride (shorts), 16B-aligned rows

typedef short short8 __attribute__((ext_vector_type(8)));
typedef short short4v __attribute__((ext_vector_type(4)));
typedef float f32x4 __attribute__((ext_vector_type(4)));

__device__ __forceinline__ unsigned int f2bf_u(float f) {
    return (__float_as_uint(f) + 0x8000u) >> 16;
}
__device__ __forceinline__ unsigned short f2bf(float f) {
    return (unsigned short)f2bf_u(f);
}

// ---------------------------------------------------------------------------
// Repack fused weights [320x256] -> bf16 fragments.  Rows 0..31 = Wq*LOG2E,
// 32..63 = Wk, 64..319 = Wv.  Also bias[320].
// ---------------------------------------------------------------------------
__global__ __launch_bounds__(256) void repack_kernel(
    const float* __restrict__ Wq, const float* __restrict__ bq,
    const float* __restrict__ Wk, const float* __restrict__ bk,
    const float* __restrict__ Wv, const float* __restrict__ bv,
    unsigned short* __restrict__ wp, float* __restrict__ bias)
{
    const int T    = blockIdx.x * 256 + threadIdx.x;   // 81920 threads
    const int j    = T & 7;
    const int lane = (T >> 3) & 63;
    const int ks   = (T >> 9) & 7;
    const int mt   = T >> 12;
    const int m = mt * 16 + (lane & 15);
    const int k = ks * 32 + ((lane >> 4) << 3) + j;
    float wv;
    if (m < 32)       wv = Wq[m * NC + k] * LOG2E;
    else if (m < 64)  wv = Wk[(m - 32) * NC + k];
    else              wv = Wv[(m - 64) * NC + k];
    wp[T] = f2bf(wv);
    if (T < NM) {
        float bb;
        if (T < 32)      bb = bq[T] * LOG2E;
        else if (T < 64) bb = bk[T - 32];
        else             bb = bv[T - 64];
        bias[T] = bb;
    }
}

// ---------------------------------------------------------------------------
// MFMA projection (unchanged): A = x (m = pixel), B = W^T.
// ---------------------------------------------------------------------------
__global__ __launch_bounds__(256, 4) void proj_kernel(
    const float* __restrict__ x,
    const unsigned short* __restrict__ wp,
    const float* __restrict__ bias,
    unsigned short* __restrict__ q_ws,
    unsigned short* __restrict__ k_ws,
    unsigned short* __restrict__ v_ws)
{
    __shared__ __align__(16) unsigned short xs[32 * XSTR];   // 16.9 KB

    const int b  = blockIdx.x >> 7;          // 128 tiles per batch
    const int n0 = (blockIdx.x & 127) << 5;
    const int t  = threadIdx.x;

    {
        const int n  = t & 31;
        const int cg = t >> 5;               // 0..7
        const float* xb = x + (size_t)b * NC * NN + n0 + n;
        #pragma unroll
        for (int it = 0; it < 8; ++it) {
            const int c = 32 * it + 4 * cg;
            const float x0 = xb[(size_t)(c + 0) * NN];
            const float x1 = xb[(size_t)(c + 1) * NN];
            const float x2 = xb[(size_t)(c + 2) * NN];
            const float x3 = xb[(size_t)(c + 3) * NN];
            uint2 pk;
            pk.x = (f2bf_u(x1) << 16) | f2bf_u(x0);
            pk.y = (f2bf_u(x3) << 16) | f2bf_u(x2);
            *(uint2*)(xs + n * XSTR + c) = pk;
        }
    }
    __syncthreads();

    const int w    = t >> 6;
    const int lane = t & 63;
    const int li = lane & 15;
    const int qd = lane >> 4;

    f32x4 acc[5][2];
    #pragma unroll
    for (int u = 0; u < 5; ++u) {
        const float bb = bias[(w + 4 * u) * 16 + li];
        acc[u][0] = (f32x4){bb, bb, bb, bb};
        acc[u][1] = (f32x4){bb, bb, bb, bb};
    }

    #pragma unroll
    for (int ks = 0; ks < 8; ++ks) {
        short8 af[2];
        #pragma unroll
        for (int mt = 0; mt < 2; ++mt)
            af[mt] = *(const short8*)(xs + (mt * 16 + li) * XSTR + ks * 32 + qd * 8);
        #pragma unroll
        for (int u = 0; u < 5; ++u) {
            const int ct = w + 4 * u;
            const short8 bf = *(const short8*)(wp + (size_t)((ct * 8 + ks) * 64 + lane) * 8);
            acc[u][0] = __builtin_amdgcn_mfma_f32_16x16x32_bf16(af[0], bf, acc[u][0], 0, 0, 0);
            acc[u][1] = __builtin_amdgcn_mfma_f32_16x16x32_bf16(af[1], bf, acc[u][1], 0, 0, 0);
        }
    }

    #pragma unroll
    for (int u = 0; u < 5; ++u) {
        const int ct = w + 4 * u;
        if (ct < 4) {
            unsigned short* dst = (ct < 2) ? q_ws : k_ws;
            const int d = (ct & 1) * 16 + li;
            #pragma unroll
            for (int mt = 0; mt < 2; ++mt)
                #pragma unroll
                for (int r = 0; r < 4; ++r) {
                    const int n = n0 + mt * 16 + 4 * qd + r;
                    dst[((size_t)b * NN + n) * ND + d] = f2bf(acc[u][mt][r]);
                }
        } else {
            const int cv = (ct - 4) * 16 + li;
            #pragma unroll
            for (int mt = 0; mt < 2; ++mt) {
                const int n = n0 + mt * 16 + 4 * qd;
                uint2 pk;
                pk.x = (f2bf_u(acc[u][mt][1]) << 16) | f2bf_u(acc[u][mt][0]);
                pk.y = (f2bf_u(acc[u][mt][3]) << 16) | f2bf_u(acc[u][mt][2]);
                *(uint2*)(v_ws + ((size_t)b * NC + cv) * NN + n) = pk;
            }
        }
    }
}

// ---------------------------------------------------------------------------
// Flash attention R11: barrier-free, LDS-free (R10 structure), register-
// budgeted so it actually fits.  4 independent waves / 256-thr block; wave w
// owns the full 64-row i-tile x 64 channels (c0=64w).
//
// R10 lesson: the design worked (0 bank conflicts, no barriers) but spilled
// ~190 B/thread/chunk (WRITE_SIZE 33MB->1.1GB): 96-reg pinned double
// prefetch + 64-reg acc exceeded the 128-arch half of the register file.
// R11 shrinks arch pressure to ~100:
//   - half-chunks of 32 j: K frags 2x8=16 regs (dbl), pk[4][2]=16 regs
//   - V slot pipeline: 4 fixed slots x 2 frags = 16 regs (was 64);
//     ct2/ct3 loaded at top of the half (hidden under S/exp phase),
//     next-half ct0/ct1 issued between PV groups
//   - no sched_barrier pins; compiler schedules + inserts waitcnts
// Math identical to R10 (passed): S = mfma_16x16x32(K,Q) leaves lane
// (li,qd) holding S[i=li][j=16jt+4qd+r]; exp2+pack yields exactly the
// B-operand fragment of v_mfma_f32_16x16x16_bf16, so P never leaves the
// lane: S-MFMA -> exp2 -> pack -> PV-MFMA.  Zero LDS, zero barriers.
// ---------------------------------------------------------------------------
__global__ __launch_bounds__(256, 2) void attn_kernel(
    const unsigned short* __restrict__ q_ws,
    const unsigned short* __restrict__ k_ws,
    const unsigned short* __restrict__ v_ws,
    float* __restrict__ out)
{
    const int b  = blockIdx.x & 7;           // batch == XCD
    const int i0 = (blockIdx.x >> 3) * 64;
    const int w    = threadIdx.x >> 6;       // 0..3
    const int lane = threadIdx.x & 63;
    const int li = lane & 15;
    const int qd = lane >> 4;
    const int c0 = 64 * w;                   // channel slice (64 ch)

    // Q fragments for the 4 i-strips (B-operand of S-MFMA: col=i, k=d)
    short8 qf[4];
    #pragma unroll
    for (int sb = 0; sb < 4; ++sb)
        qf[sb] = *(const short8*)(q_ws + ((size_t)b * NN + i0 + 16 * sb + li) * ND + qd * 8);

    // K base: A-operand of S-MFMA (row=j, k=d)
    const unsigned short* kb = k_ws + ((size_t)b * NN + li) * ND + qd * 8;
    // V bases per c-tile: A-operand of PV-MFMA16 (row=c, k=j -> qd*4)
    const unsigned short* vrow[4];
    #pragma unroll
    for (int ct = 0; ct < 4; ++ct)
        vrow[ct] = v_ws + ((size_t)b * NC + c0 + 16 * ct + li) * NN + qd * 4;

    f32x4 o[4][4];                           // [i-strip][c-tile] (acc regs)
    #pragma unroll
    for (int sb = 0; sb < 4; ++sb)
        #pragma unroll
        for (int ct = 0; ct < 4; ++ct)
            o[sb][ct] = (f32x4){0.f, 0.f, 0.f, 0.f};
    float l_loc[4] = {0.f, 0.f, 0.f, 0.f};
    const f32x4 z4 = {0.f, 0.f, 0.f, 0.f};

    short8 kHA[2], kHB[2];                   // K frags, half-chunk, dbl-buf
    uint2  vs[4][2];                         // V slots: [ct][jt]
    uint2  pk[4][2];                         // packed P: [sb][jt]

    // One 32-j half-chunk at j0, K frags kc (current), kn (next prefetched).
    auto HALF = [&](int j0, short8 (&kc)[2], short8 (&kn)[2]) {
        // V ct2/ct3 for THIS half: issue at top, used after the S phase.
        vs[2][0] = *(const uint2*)(vrow[2] + j0);
        vs[2][1] = *(const uint2*)(vrow[2] + j0 + 16);
        vs[3][0] = *(const uint2*)(vrow[3] + j0);
        vs[3][1] = *(const uint2*)(vrow[3] + j0 + 16);
        // S phase: 8 MFMA + 32 exp2 + pack
        #pragma unroll
        for (int sb = 0; sb < 4; ++sb)
            #pragma unroll
            for (int jt = 0; jt < 2; ++jt) {
                const f32x4 s = __builtin_amdgcn_mfma_f32_16x16x32_bf16(kc[jt], qf[sb], z4, 0, 0, 0);
                const float p0 = __builtin_amdgcn_exp2f(s[0]);
                const float p1 = __builtin_amdgcn_exp2f(s[1]);
                const float p2 = __builtin_amdgcn_exp2f(s[2]);
                const float p3 = __builtin_amdgcn_exp2f(s[3]);
                l_loc[sb] += (p0 + p1) + (p2 + p3);
                const unsigned u0 = __float_as_uint(p0) + 0x8000u;
                const unsigned u1 = __float_as_uint(p1) + 0x8000u;
                const unsigned u2 = __float_as_uint(p2) + 0x8000u;
                const unsigned u3 = __float_as_uint(p3) + 0x8000u;
                pk[sb][jt].x = __builtin_amdgcn_perm(u1, u0, 0x07060302u);
                pk[sb][jt].y = __builtin_amdgcn_perm(u3, u2, 0x07060302u);
            }
        // K for next half (used after full PV phase)
        kn[0] = *(const short8*)(kb + (size_t)(j0 + 32) * ND);
        kn[1] = *(const short8*)(kb + (size_t)(j0 + 48) * ND);
        // PV phase: 4 ct-groups of 8 MFMA; next-half ct0/ct1 loads between
        #pragma unroll
        for (int sb = 0; sb < 4; ++sb)
            #pragma unroll
            for (int jt = 0; jt < 2; ++jt)
                o[sb][0] = __builtin_amdgcn_mfma_f32_16x16x16bf16_1k(
                    __builtin_bit_cast(short4v, vs[0][jt]),
                    __builtin_bit_cast(short4v, pk[sb][jt]), o[sb][0], 0, 0, 0);
        vs[0][0] = *(const uint2*)(vrow[0] + j0 + 32);
        vs[0][1] = *(const uint2*)(vrow[0] + j0 + 48);
        #pragma unroll
        for (int sb = 0; sb < 4; ++sb)
            #pragma unroll
            for (int jt = 0; jt < 2; ++jt)
                o[sb][1] = __builtin_amdgcn_mfma_f32_16x16x16bf16_1k(
                    __builtin_bit_cast(short4v, vs[1][jt]),
                    __builtin_bit_cast(short4v, pk[sb][jt]), o[sb][1], 0, 0, 0);
        vs[1][0] = *(const uint2*)(vrow[1] + j0 + 32);
        vs[1][1] = *(const uint2*)(vrow[1] + j0 + 48);
        #pragma unroll
        for (int sb = 0; sb < 4; ++sb)
            #pragma unroll
            for (int jt = 0; jt < 2; ++jt)
                o[sb][2] = __builtin_amdgcn_mfma_f32_16x16x16bf16_1k(
                    __builtin_bit_cast(short4v, vs[2][jt]),
                    __builtin_bit_cast(short4v, pk[sb][jt]), o[sb][2], 0, 0, 0);
        #pragma unroll
        for (int sb = 0; sb < 4; ++sb)
            #pragma unroll
            for (int jt = 0; jt < 2; ++jt)
                o[sb][3] = __builtin_amdgcn_mfma_f32_16x16x16bf16_1k(
                    __builtin_bit_cast(short4v, vs[3][jt]),
                    __builtin_bit_cast(short4v, pk[sb][jt]), o[sb][3], 0, 0, 0);
    };

    // ---- prologue: K(half 0) + V ct0/ct1(half 0) ----
    kHA[0] = *(const short8*)(kb);
    kHA[1] = *(const short8*)(kb + (size_t)16 * ND);
    vs[0][0] = *(const uint2*)(vrow[0]);
    vs[0][1] = *(const uint2*)(vrow[0] + 16);
    vs[1][0] = *(const uint2*)(vrow[1]);
    vs[1][1] = *(const uint2*)(vrow[1] + 16);

    // ---- main loop: 64 iterations x 2 half-chunks (tail prefetches read
    // harmlessly into the adjacent wp region of d_ws; never consumed) ----
    #pragma unroll 1
    for (int t = 0; t < 64; ++t) {
        HALF(64 * t,      kHA, kHB);
        HALF(64 * t + 32, kHB, kHA);
    }

    // ---- l reduction: fully intra-wave (sum over qd groups) ----
    #pragma unroll
    for (int sb = 0; sb < 4; ++sb) {
        l_loc[sb] += __shfl_xor(l_loc[sb], 16, 64);
        l_loc[sb] += __shfl_xor(l_loc[sb], 32, 64);
    }

    #pragma unroll
    for (int sb = 0; sb < 4; ++sb) {
        const float linv = 1.0f / l_loc[sb];
        #pragma unroll
        for (int ct = 0; ct < 4; ++ct) {
            const int c = c0 + ct * 16 + qd * 4;
            float* op = out + ((size_t)b * NC + c) * NN + i0 + 16 * sb + li;
            #pragma unroll
            for (int r = 0; r < 4; ++r)
                op[(size_t)r * NN] = o[sb][ct][r] * linv;
        }
    }
}

// ---------------------------------------------------------------------------
extern "C" void kernel_launch(void* const* d_in, const int* in_sizes, int n_in,
                              void* d_out, int out_size, void* d_ws, size_t ws_size,
                              hipStream_t stream) {
    const float* x  = (const float*)d_in[0];
    const float* Wq = (const float*)d_in[1];
    const float* bq = (const float*)d_in[2];
    const float* Wk = (const float*)d_in[3];
    const float* bk = (const float*)d_in[4];
    const float* Wv = (const float*)d_in[5];
    const float* bv = (const float*)d_in[6];
    float* out = (float*)d_out;

    unsigned short* q_ws = (unsigned short*)d_ws;            // 2 MB
    unsigned short* k_ws = q_ws + (size_t)NB * NN * ND;      // 2 MB
    unsigned short* v_ws = k_ws + (size_t)NB * NN * ND;      // 16 MB
    unsigned short* wp   = v_ws + (size_t)NB * NC * NN;      // 160 KB
    float*          bias = (float*)(wp + (size_t)NM * NC);   // 1.25 KB

    repack_kernel<<<NM * NC / 256, 256, 0, stream>>>(Wq, bq, Wk, bk, Wv, bv, wp, bias);
    proj_kernel<<<NB * (NN / 32), 256, 0, stream>>>(x, wp, bias, q_ws, k_ws, v_ws);
    attn_kernel<<<NB * (NN / 64), 256, 0, stream>>>(q_ws, k_ws, v_ws, out);
}

// Round 5
// 227.362 us; speedup vs baseline: 2.5863x; 1.5793x over previous
//
#include <hip/hip_runtime.h>
#include <math.h>

#define NB 8
#define NC 256
#define ND 32
#define NN 4096
#define NM 320                 // fused rows: 32 q + 32 k + 256 v
#define LOG2E 1.44269504088896f
#define XSTR 264               // proj LDS row stride (shorts), 16B-aligned rows

typedef short short8 __attribute__((ext_vector_type(8)));
typedef short short4v __attribute__((ext_vector_type(4)));
typedef float f32x4 __attribute__((ext_vector_type(4)));

__device__ __forceinline__ unsigned int f2bf_u(float f) {
    return (__float_as_uint(f) + 0x8000u) >> 16;
}
__device__ __forceinline__ unsigned short f2bf(float f) {
    return (unsigned short)f2bf_u(f);
}

// ---------------------------------------------------------------------------
// Repack fused weights [320x256] -> bf16 fragments.  Rows 0..31 = Wq*LOG2E,
// 32..63 = Wk, 64..319 = Wv.  Also bias[320].
// ---------------------------------------------------------------------------
__global__ __launch_bounds__(256) void repack_kernel(
    const float* __restrict__ Wq, const float* __restrict__ bq,
    const float* __restrict__ Wk, const float* __restrict__ bk,
    const float* __restrict__ Wv, const float* __restrict__ bv,
    unsigned short* __restrict__ wp, float* __restrict__ bias)
{
    const int T    = blockIdx.x * 256 + threadIdx.x;   // 81920 threads
    const int j    = T & 7;
    const int lane = (T >> 3) & 63;
    const int ks   = (T >> 9) & 7;
    const int mt   = T >> 12;
    const int m = mt * 16 + (lane & 15);
    const int k = ks * 32 + ((lane >> 4) << 3) + j;
    float wv;
    if (m < 32)       wv = Wq[m * NC + k] * LOG2E;
    else if (m < 64)  wv = Wk[(m - 32) * NC + k];
    else              wv = Wv[(m - 64) * NC + k];
    wp[T] = f2bf(wv);
    if (T < NM) {
        float bb;
        if (T < 32)      bb = bq[T] * LOG2E;
        else if (T < 64) bb = bk[T - 32];
        else             bb = bv[T - 64];
        bias[T] = bb;
    }
}

// ---------------------------------------------------------------------------
// MFMA projection.  A = x (m = pixel), B = W^T.  R12: K and V outputs are
// written in MFMA-FRAGMENT-LINEAR layout so the attn kernel's loads are
// fully coalesced (one contiguous 512B/1KB transaction per fragment):
//   K: [b][jtile(256)][lane(64)][8]  lane = (d>>3)*16 + (j&15), elem d&7
//   V: [b][ctile(16)][jtile(256)][lane(64)][4] lane = ((j>>2)&3)*16 + (c&15)
// ---------------------------------------------------------------------------
__global__ __launch_bounds__(256, 4) void proj_kernel(
    const float* __restrict__ x,
    const unsigned short* __restrict__ wp,
    const float* __restrict__ bias,
    unsigned short* __restrict__ q_ws,
    unsigned short* __restrict__ k_ws,
    unsigned short* __restrict__ v_ws)
{
    __shared__ __align__(16) unsigned short xs[32 * XSTR];   // 16.9 KB

    const int b  = blockIdx.x >> 7;          // 128 tiles per batch
    const int n0 = (blockIdx.x & 127) << 5;
    const int t  = threadIdx.x;

    {
        const int n  = t & 31;
        const int cg = t >> 5;               // 0..7
        const float* xb = x + (size_t)b * NC * NN + n0 + n;
        #pragma unroll
        for (int it = 0; it < 8; ++it) {
            const int c = 32 * it + 4 * cg;
            const float x0 = xb[(size_t)(c + 0) * NN];
            const float x1 = xb[(size_t)(c + 1) * NN];
            const float x2 = xb[(size_t)(c + 2) * NN];
            const float x3 = xb[(size_t)(c + 3) * NN];
            uint2 pk;
            pk.x = (f2bf_u(x1) << 16) | f2bf_u(x0);
            pk.y = (f2bf_u(x3) << 16) | f2bf_u(x2);
            *(uint2*)(xs + n * XSTR + c) = pk;
        }
    }
    __syncthreads();

    const int w    = t >> 6;
    const int lane = t & 63;
    const int li = lane & 15;
    const int qd = lane >> 4;

    f32x4 acc[5][2];
    #pragma unroll
    for (int u = 0; u < 5; ++u) {
        const float bb = bias[(w + 4 * u) * 16 + li];
        acc[u][0] = (f32x4){bb, bb, bb, bb};
        acc[u][1] = (f32x4){bb, bb, bb, bb};
    }

    #pragma unroll
    for (int ks = 0; ks < 8; ++ks) {
        short8 af[2];
        #pragma unroll
        for (int mt = 0; mt < 2; ++mt)
            af[mt] = *(const short8*)(xs + (mt * 16 + li) * XSTR + ks * 32 + qd * 8);
        #pragma unroll
        for (int u = 0; u < 5; ++u) {
            const int ct = w + 4 * u;
            const short8 bf = *(const short8*)(wp + (size_t)((ct * 8 + ks) * 64 + lane) * 8);
            acc[u][0] = __builtin_amdgcn_mfma_f32_16x16x32_bf16(af[0], bf, acc[u][0], 0, 0, 0);
            acc[u][1] = __builtin_amdgcn_mfma_f32_16x16x32_bf16(af[1], bf, acc[u][1], 0, 0, 0);
        }
    }

    #pragma unroll
    for (int u = 0; u < 5; ++u) {
        const int ct = w + 4 * u;
        if (ct < 2) {
            // Q: row-major [b][n][d] (read once by attn; layout uncritical)
            const int d = ct * 16 + li;
            #pragma unroll
            for (int mt = 0; mt < 2; ++mt)
                #pragma unroll
                for (int r = 0; r < 4; ++r) {
                    const int n = n0 + mt * 16 + 4 * qd + r;
                    q_ws[((size_t)b * NN + n) * ND + d] = f2bf(acc[u][mt][r]);
                }
        } else if (ct < 4) {
            // K: fragment-linear
            const int d = (ct & 1) * 16 + li;
            #pragma unroll
            for (int mt = 0; mt < 2; ++mt)
                #pragma unroll
                for (int r = 0; r < 4; ++r) {
                    const int n = n0 + mt * 16 + 4 * qd + r;
                    k_ws[((size_t)(b * 256 + (n >> 4)) * 64 + (d >> 3) * 16 + (n & 15)) * 8 + (d & 7)]
                        = f2bf(acc[u][mt][r]);
                }
        } else {
            // V: fragment-linear; uint2 = V[cv][n..n+3] -> lane (qd*16+li), 4 elems
            const int ctv = ct - 4;              // V c-tile 0..15
            #pragma unroll
            for (int mt = 0; mt < 2; ++mt) {
                const int jt = (n0 >> 4) + mt;
                uint2 pk;
                pk.x = (f2bf_u(acc[u][mt][1]) << 16) | f2bf_u(acc[u][mt][0]);
                pk.y = (f2bf_u(acc[u][mt][3]) << 16) | f2bf_u(acc[u][mt][2]);
                *(uint2*)(v_ws + (((size_t)(b * 16 + ctv) * 256 + jt) * 64 + qd * 16 + li) * 4) = pk;
            }
        }
    }
}

// ---------------------------------------------------------------------------
// Flash attention R12: barrier-free, LDS-free (R11 structure) + fragment-
// linear K/V so every steady-state load is ONE coalesced transaction.
//
// R11 lesson: no spills, 0 conflicts, but 47% of cycles idle at 2 waves/SIMD
// — every K/V load was a 16-cache-line scatter (li-rows 8KB apart), ~160
// line-requests per wave-half, blowing L2 latency past the slot pipeline's
// cover; the K edge (loaded after S(h), used at S(h+1)) stalled every half.
// R12: K frags = contiguous 1KB at lane*8; V frags = contiguous 512B at
// lane*4 (proj writes them in fragment order).  kn prefetch moved to top of
// half (double-buffered, no WAR) for an extra ~300cyc of cover.
// Math identical to R10/R11 (passed): S = mfma_16x16x32(K,Q) leaves lane
// (li,qd) with S[i=li][j=16jt+4qd+r]; exp2+pack is exactly the B-fragment
// of v_mfma_f32_16x16x16bf16_1k, so P never leaves the lane.
// ---------------------------------------------------------------------------
__global__ __launch_bounds__(256, 2) void attn_kernel(
    const unsigned short* __restrict__ q_ws,
    const unsigned short* __restrict__ k_ws,
    const unsigned short* __restrict__ v_ws,
    float* __restrict__ out)
{
    const int b  = blockIdx.x & 7;           // batch == XCD
    const int i0 = (blockIdx.x >> 3) * 64;
    const int w    = threadIdx.x >> 6;       // 0..3
    const int lane = threadIdx.x & 63;
    const int li = lane & 15;
    const int qd = lane >> 4;
    const int c0 = 64 * w;                   // channel slice (64 ch)

    // Q fragments for the 4 i-strips (B-operand of S-MFMA: col=i, k=d)
    short8 qf[4];
    #pragma unroll
    for (int sb = 0; sb < 4; ++sb)
        qf[sb] = *(const short8*)(q_ws + ((size_t)b * NN + i0 + 16 * sb + li) * ND + qd * 8);

    // Fragment-linear bases: K frag = 512 shorts, V frag = 256 shorts
    const unsigned short* kfb = k_ws + ((size_t)b * 256 * 64 + lane) * 8;
    const unsigned short* vtb[4];
    #pragma unroll
    for (int ct = 0; ct < 4; ++ct)
        vtb[ct] = v_ws + (((size_t)(b * 16 + (c0 >> 4) + ct) * 256) * 64 + lane) * 4;

    f32x4 o[4][4];                           // [i-strip][c-tile] (acc regs)
    #pragma unroll
    for (int sb = 0; sb < 4; ++sb)
        #pragma unroll
        for (int ct = 0; ct < 4; ++ct)
            o[sb][ct] = (f32x4){0.f, 0.f, 0.f, 0.f};
    float l_loc[4] = {0.f, 0.f, 0.f, 0.f};
    const f32x4 z4 = {0.f, 0.f, 0.f, 0.f};

    short8 kHA[2], kHB[2];                   // K frags, half-chunk, dbl-buf
    uint2  vs[4][2];                         // V slots: [ct][jt]
    uint2  pk[4][2];                         // packed P: [sb][jt]

    // One 32-j half-chunk at j0 (frag f0 = j0/16); kc current, kn next.
    auto HALF = [&](int j0, short8 (&kc)[2], short8 (&kn)[2]) {
        const size_t f0 = (size_t)(j0 >> 4);
        // next-half K at TOP (double-buffered, no WAR): max cover
        kn[0] = *(const short8*)(kfb + (f0 + 2) * 512);
        kn[1] = *(const short8*)(kfb + (f0 + 3) * 512);
        // V ct2/ct3 for THIS half: used after the S phase.
        vs[2][0] = *(const uint2*)(vtb[2] + (f0    ) * 256);
        vs[2][1] = *(const uint2*)(vtb[2] + (f0 + 1) * 256);
        vs[3][0] = *(const uint2*)(vtb[3] + (f0    ) * 256);
        vs[3][1] = *(const uint2*)(vtb[3] + (f0 + 1) * 256);
        // S phase: 8 MFMA + 32 exp2 + pack
        #pragma unroll
        for (int sb = 0; sb < 4; ++sb)
            #pragma unroll
            for (int jt = 0; jt < 2; ++jt) {
                const f32x4 s = __builtin_amdgcn_mfma_f32_16x16x32_bf16(kc[jt], qf[sb], z4, 0, 0, 0);
                const float p0 = __builtin_amdgcn_exp2f(s[0]);
                const float p1 = __builtin_amdgcn_exp2f(s[1]);
                const float p2 = __builtin_amdgcn_exp2f(s[2]);
                const float p3 = __builtin_amdgcn_exp2f(s[3]);
                l_loc[sb] += (p0 + p1) + (p2 + p3);
                const unsigned u0 = __float_as_uint(p0) + 0x8000u;
                const unsigned u1 = __float_as_uint(p1) + 0x8000u;
                const unsigned u2 = __float_as_uint(p2) + 0x8000u;
                const unsigned u3 = __float_as_uint(p3) + 0x8000u;
                pk[sb][jt].x = __builtin_amdgcn_perm(u1, u0, 0x07060302u);
                pk[sb][jt].y = __builtin_amdgcn_perm(u3, u2, 0x07060302u);
            }
        // PV phase: 4 ct-groups of 8 MFMA; next-half ct0/ct1 loads between
        #pragma unroll
        for (int sb = 0; sb < 4; ++sb)
            #pragma unroll
            for (int jt = 0; jt < 2; ++jt)
                o[sb][0] = __builtin_amdgcn_mfma_f32_16x16x16bf16_1k(
                    __builtin_bit_cast(short4v, vs[0][jt]),
                    __builtin_bit_cast(short4v, pk[sb][jt]), o[sb][0], 0, 0, 0);
        vs[0][0] = *(const uint2*)(vtb[0] + (f0 + 2) * 256);
        vs[0][1] = *(const uint2*)(vtb[0] + (f0 + 3) * 256);
        #pragma unroll
        for (int sb = 0; sb < 4; ++sb)
            #pragma unroll
            for (int jt = 0; jt < 2; ++jt)
                o[sb][1] = __builtin_amdgcn_mfma_f32_16x16x16bf16_1k(
                    __builtin_bit_cast(short4v, vs[1][jt]),
                    __builtin_bit_cast(short4v, pk[sb][jt]), o[sb][1], 0, 0, 0);
        vs[1][0] = *(const uint2*)(vtb[1] + (f0 + 2) * 256);
        vs[1][1] = *(const uint2*)(vtb[1] + (f0 + 3) * 256);
        #pragma unroll
        for (int sb = 0; sb < 4; ++sb)
            #pragma unroll
            for (int jt = 0; jt < 2; ++jt)
                o[sb][2] = __builtin_amdgcn_mfma_f32_16x16x16bf16_1k(
                    __builtin_bit_cast(short4v, vs[2][jt]),
                    __builtin_bit_cast(short4v, pk[sb][jt]), o[sb][2], 0, 0, 0);
        #pragma unroll
        for (int sb = 0; sb < 4; ++sb)
            #pragma unroll
            for (int jt = 0; jt < 2; ++jt)
                o[sb][3] = __builtin_amdgcn_mfma_f32_16x16x16bf16_1k(
                    __builtin_bit_cast(short4v, vs[3][jt]),
                    __builtin_bit_cast(short4v, pk[sb][jt]), o[sb][3], 0, 0, 0);
    };

    // ---- prologue: K(half 0) + V ct0/ct1(half 0) ----
    kHA[0] = *(const short8*)(kfb);
    kHA[1] = *(const short8*)(kfb + 512);
    vs[0][0] = *(const uint2*)(vtb[0]);
    vs[0][1] = *(const uint2*)(vtb[0] + 256);
    vs[1][0] = *(const uint2*)(vtb[1]);
    vs[1][1] = *(const uint2*)(vtb[1] + 256);

    // ---- main loop: 64 iterations x 2 half-chunks (tail prefetches read
    // harmlessly into adjacent d_ws regions; never consumed) ----
    #pragma unroll 1
    for (int t = 0; t < 64; ++t) {
        HALF(64 * t,      kHA, kHB);
        HALF(64 * t + 32, kHB, kHA);
    }

    // ---- l reduction: fully intra-wave (sum over qd groups) ----
    #pragma unroll
    for (int sb = 0; sb < 4; ++sb) {
        l_loc[sb] += __shfl_xor(l_loc[sb], 16, 64);
        l_loc[sb] += __shfl_xor(l_loc[sb], 32, 64);
    }

    #pragma unroll
    for (int sb = 0; sb < 4; ++sb) {
        const float linv = 1.0f / l_loc[sb];
        #pragma unroll
        for (int ct = 0; ct < 4; ++ct) {
            const int c = c0 + ct * 16 + qd * 4;
            float* op = out + ((size_t)b * NC + c) * NN + i0 + 16 * sb + li;
            #pragma unroll
            for (int r = 0; r < 4; ++r)
                op[(size_t)r * NN] = o[sb][ct][r] * linv;
        }
    }
}

// ---------------------------------------------------------------------------
extern "C" void kernel_launch(void* const* d_in, const int* in_sizes, int n_in,
                              void* d_out, int out_size, void* d_ws, size_t ws_size,
                              hipStream_t stream) {
    const float* x  = (const float*)d_in[0];
    const float* Wq = (const float*)d_in[1];
    const float* bq = (const float*)d_in[2];
    const float* Wk = (const float*)d_in[3];
    const float* bk = (const float*)d_in[4];
    const float* Wv = (const float*)d_in[5];
    const float* bv = (const float*)d_in[6];
    float* out = (float*)d_out;

    unsigned short* q_ws = (unsigned short*)d_ws;            // 2 MB
    unsigned short* k_ws = q_ws + (size_t)NB * NN * ND;      // 2 MB
    unsigned short* v_ws = k_ws + (size_t)NB * NN * ND;      // 16 MB
    unsigned short* wp   = v_ws + (size_t)NB * NC * NN;      // 160 KB
    float*          bias = (float*)(wp + (size_t)NM * NC);   // 1.25 KB

    repack_kernel<<<NM * NC / 256, 256, 0, stream>>>(Wq, bq, Wk, bk, Wv, bv, wp, bias);
    proj_kernel<<<NB * (NN / 32), 256, 0, stream>>>(x, wp, bias, q_ws, k_ws, v_ws);
    attn_kernel<<<NB * (NN / 64), 256, 0, stream>>>(q_ws, k_ws, v_ws, out);
}